// Round 16
// baseline (4290.545 us; speedup 1.0000x reference)
//
#include <hip/hip_runtime.h>
#include <hip/hip_bf16.h>
#include <stdint.h>

#define B_ 128
#define T_ 256
#define IN_ 512
#define H_ 1024
#define G4_ 4096
#define TC_ 64              // time chunk
#define NCHUNK_ (T_ / TC_)

typedef __bf16 bf16x8 __attribute__((ext_vector_type(8)));
typedef float f32x4 __attribute__((ext_vector_type(4)));
typedef uint32_t u32x4 __attribute__((ext_vector_type(4)));

#define AS1U(p) ((const __attribute__((address_space(1))) unsigned int*)(p))
#define AS3U(p) ((__attribute__((address_space(3))) unsigned int*)(p))

__device__ __forceinline__ uint16_t f2bf(float f) {
  union { float f; uint32_t u; } v; v.f = f;
  uint32_t r = (v.u + 0x7fffu + ((v.u >> 16) & 1u)) >> 16;
  return (uint16_t)r;
}
__device__ __forceinline__ float bf2f(uint16_t h) {
  union { uint32_t u; float f; } v; v.u = ((uint32_t)h) << 16;
  return v.f;
}
__device__ __forceinline__ float sigmoid_f(float x) {
  return 1.f / (1.f + __expf(-x));
}
__device__ __forceinline__ float tanh_f(float x) {
  x = fminf(15.f, fmaxf(-15.f, x));
  float e = __expf(2.f * x);
  return (e - 1.f) / (e + 1.f);
}

// ---------------- prep kernels ----------------
__global__ void k_f32_to_bf16(const float* __restrict__ src, uint16_t* __restrict__ dst, int n) {
  int i = (blockIdx.x * blockDim.x + threadIdx.x) * 4;
  if (i >= n) return;
  float4 v = *(const float4*)(src + i);
  ushort4 o;
  o.x = f2bf(v.x); o.y = f2bf(v.y); o.z = f2bf(v.z); o.w = f2bf(v.w);
  *(ushort4*)(dst + i) = o;
}

__global__ void k_bias(const float* __restrict__ a, const float* __restrict__ b, float* __restrict__ o) {
  int i = blockIdx.x * blockDim.x + threadIdx.x;
  if (i < G4_) o[i] = a[i] + b[i];
}

// Rearrange w_hh (fp32 [4096][1024]) into per-(slice,wave) MFMA B-fragments, bf16.
__global__ void k_whh_frag(const float* __restrict__ whh, uint16_t* __restrict__ dst) {
  int t = blockIdx.x * blockDim.x + threadIdx.x;   // 0..524287
  int lane = t & 63;
  int kk = (t >> 6) & 15;
  int w  = (t >> 10) & 15;
  int s5 = t >> 14;
  int nt = w & 7, kh = w >> 3;
  int row = (nt >> 1) * 1024 + s5 * 32 + (nt & 1) * 16 + (lane & 15);
  int col = kh * 512 + kk * 32 + ((lane >> 4) << 3);
  const float* sp = whh + (size_t)row * H_ + col;
  uint16_t o[8];
  #pragma unroll
  for (int j = 0; j < 8; ++j) o[j] = f2bf(sp[j]);
  uint4 pk;
  __builtin_memcpy(&pk, o, 16);
  *(uint4*)(dst + (size_t)t * 8) = pk;
}

// ---------------- GEMM body (1024 threads, 128x128 tile) ----------------
// 16 waves: w<8 stage A (global_load_lds bf16, or f32->bf16 convert for Adt=1),
// w>=8 stage B. Each wave computes a 32x32 output (acc 2x2). Cs aliases As/Bs.
// A rows map xr -> gm = mx*512 + t0 + ((xr>>6)<<8) + (xr&63)  (b*T + t0 + tl).
__device__ __forceinline__ void gemm_body(
    int tile, int tid, char* SM, const void* A, int Adt,
    const uint16_t* __restrict__ W, const float* __restrict__ bias,
    uint16_t* __restrict__ xp, int K, int t0)
{
  uint16_t* As = (uint16_t*)SM;            // 8 KiB
  uint16_t* Bs = (uint16_t*)(SM + 8192);   // 8 KiB
  uint16_t* Cs = (uint16_t*)SM;            // [128][136] epilogue alias
  const int l = tid & 63;
  const int w = tid >> 6;
  const int mx = tile >> 5;                // 0..63
  const int n0 = (tile & 31) << 7;         // 0..3968
  const int wm = (w >> 2) << 5;
  const int wn = (w & 3) << 5;

  f32x4 acc[2][2] = {};

  for (int k0 = 0; k0 < K; k0 += 32) {
    __syncthreads();
    if (w < 8) {
      if (Adt == 0) {
        const int loff = w * 1024 + l * 16;
        const int row = loff >> 6, colb = loff & 63;
        const int gm = mx * 512 + t0 + ((row >> 6) << 8) + (row & 63);
        const uint16_t* ga = (const uint16_t*)A + (size_t)gm * K + k0 + (colb >> 1);
        __builtin_amdgcn_global_load_lds(AS1U(ga), AS3U((char*)As + loff), 16, 0, 0);
      } else {
        const int idx = (w * 64 + l) * 8;      // f32 elem index in 128x32 tile
        const int row = idx >> 5;
        const int col = idx & 31;
        const int gm = mx * 512 + t0 + ((row >> 6) << 8) + (row & 63);
        const float* sp = (const float*)A + (size_t)gm * K + k0 + col;
        float4 v0 = *(const float4*)sp;
        float4 v1 = *(const float4*)(sp + 4);
        uint16_t o[8] = {f2bf(v0.x), f2bf(v0.y), f2bf(v0.z), f2bf(v0.w),
                         f2bf(v1.x), f2bf(v1.y), f2bf(v1.z), f2bf(v1.w)};
        uint4 pk; __builtin_memcpy(&pk, o, 16);
        *(uint4*)&As[row * 32 + col] = pk;
      }
    } else {
      const int loff = (w - 8) * 1024 + l * 16;
      const int row = loff >> 6, colb = loff & 63;
      const uint16_t* gb = W + (size_t)(n0 + row) * K + k0 + (colb >> 1);
      __builtin_amdgcn_global_load_lds(AS1U(gb), AS3U((char*)Bs + loff), 16, 0, 0);
    }
    __syncthreads();
    bf16x8 af[2], bfr[2];
    #pragma unroll
    for (int i = 0; i < 2; ++i)
      af[i] = *(const bf16x8*)&As[(wm + i * 16 + (l & 15)) * 32 + ((l >> 4) << 3)];
    #pragma unroll
    for (int j = 0; j < 2; ++j)
      bfr[j] = *(const bf16x8*)&Bs[(wn + j * 16 + (l & 15)) * 32 + ((l >> 4) << 3)];
    #pragma unroll
    for (int i = 0; i < 2; ++i)
      #pragma unroll
      for (int j = 0; j < 2; ++j)
        acc[i][j] = __builtin_amdgcn_mfma_f32_16x16x32_bf16(af[i], bfr[j], acc[i][j], 0, 0, 0);
  }
  __syncthreads();   // fragment reads done -> Cs may overwrite As/Bs

  #pragma unroll
  for (int i = 0; i < 2; ++i) {
    const int row = wm + i * 16 + ((l >> 4) << 2);
    #pragma unroll
    for (int j = 0; j < 2; ++j) {
      const int col = wn + j * 16 + (l & 15);
      const float bv = bias[n0 + col];
      #pragma unroll
      for (int r = 0; r < 4; ++r)
        Cs[(row + r) * 136 + col] = f2bf(acc[i][j][r] + bv);
    }
  }
  __syncthreads();
  #pragma unroll
  for (int p = 0; p < 2; ++p) {
    const int row = p * 64 + (tid >> 4);
    uint4 v = *(const uint4*)&Cs[row * 136 + (tid & 15) * 8];
    *(uint4*)(xp + (size_t)(mx * 128 + row) * G4_ + n0 + (tid & 15) * 8) = v;
  }
}

// ---------------- LSTM body (round-11/15 protocol verbatim, 203us) ----------
__device__ __forceinline__ void lstm_body(
    int bid, int tid, char* SM,
    const uint16_t* __restrict__ whhf, const uint16_t* __restrict__ xp,
    uint16_t* __restrict__ seq, uint32_t* __restrict__ hbuf,
    float* __restrict__ cbuf, unsigned int* __restrict__ flags, int t0, int sall)
{
  uint16_t* Astg = (uint16_t*)SM;                        // 32 KiB swizzled
  float (*part)[8][16][17] = (float(*)[8][16][17])(SM + 32768);  // 17.4 KiB
  const int l = tid & 63;
  const int w = tid >> 6;
  const int nt = w & 7;
  const int kh = w >> 3;
  const int g = bid & 7;
  const int s5 = bid >> 3;
  const int U0 = s5 * 32;
  const int gs0 = g * 16;

  unsigned int* gflag = flags + g * 32;

  bf16x8 bfr[16];
  {
    const uint16_t* wp = whhf + (size_t)(s5 * 16 + w) * 8192 + l * 8;
    #pragma unroll
    for (int kk = 0; kk < 16; ++kk)
      bfr[kk] = *(const bf16x8*)(wp + kk * 512);
  }

  const int u = tid & 31;
  const int smg = (tid >> 5) & 15;
  float cc = 0.f;
  if (tid < 512) cc = cbuf[(size_t)(gs0 + smg) * H_ + U0 + u];

  uint16_t x0 = 0, x1 = 0, x2 = 0, x3 = 0;
  if (tid < 512) {
    const uint16_t* p = xp + ((size_t)(gs0 + smg) * TC_ + 0) * G4_ + U0 + u;
    x0 = p[0]; x1 = p[1024]; x2 = p[2048]; x3 = p[3072];
  }

  auto stage_fused = [&](int tl) {
    const int par = tl & 1;
    const unsigned tgt = (unsigned)tl;
    const char* src = (const char*)hbuf + (size_t)par * (B_ * H_ * 2)
                      + (size_t)(gs0 + w) * 2048 + (size_t)l * 32;
    const unsigned int* fp = gflag + (l >> 1);
    u32x4 q0, q1;
    unsigned fv;
    do {
      asm volatile(
        "global_load_dword %0, %3, off sc0 sc1\n\t"
        "global_load_dwordx4 %1, %4, off sc0 sc1\n\t"
        "global_load_dwordx4 %2, %4, off offset:16 sc0 sc1\n\t"
        "s_waitcnt vmcnt(0)"
        : "=&v"(fv), "=&v"(q0), "=&v"(q1)
        : "v"(fp), "v"(src)
        : "memory");
      if (fv >= tgt) break;
      __builtin_amdgcn_s_sleep(1);
    } while (true);
    const int base = 512 * l + ((w ^ (l & 7)) << 4);
    *(u32x4*)((char*)Astg + base) = q0;
    *(u32x4*)((char*)Astg + base + 256) = q1;
  };

  stage_fused(0);
  __syncthreads();

  for (int tl = 0; tl < TC_; ++tl) {
    const int par = tl & 1;

    f32x4 e0 = {0.f, 0.f, 0.f, 0.f};
    f32x4 e1 = {0.f, 0.f, 0.f, 0.f};
    #pragma unroll
    for (int kk = 0; kk < 16; kk += 2) {
      const int c0 = kh * 64 + kk * 4 + (l >> 4);
      const int c1 = c0 + 4;
      const int sw0 = (l & 15) ^ ((2 * kk + (l >> 5)) & 7);
      const int sw1 = (l & 15) ^ ((2 * (kk + 1) + (l >> 5)) & 7);
      bf16x8 a0 = *(const bf16x8*)((const char*)Astg + ((size_t)(c0 * 16 + sw0) << 4));
      bf16x8 a1 = *(const bf16x8*)((const char*)Astg + ((size_t)(c1 * 16 + sw1) << 4));
      e0 = __builtin_amdgcn_mfma_f32_16x16x32_bf16(a0, bfr[kk],     e0, 0, 0, 0);
      e1 = __builtin_amdgcn_mfma_f32_16x16x32_bf16(a1, bfr[kk + 1], e1, 0, 0, 0);
    }
    f32x4 e = e0 + e1;
    #pragma unroll
    for (int r = 0; r < 4; ++r)
      part[kh][nt][((l >> 4) << 2) + r][l & 15] = e[r];
    __syncthreads();   // A

    if (tid < 512) {
      const int sub = u >> 4, uc = u & 15;
      float gi = part[0][0 + sub][smg][uc] + part[1][0 + sub][smg][uc] + bf2f(x0);
      float gf = part[0][2 + sub][smg][uc] + part[1][2 + sub][smg][uc] + bf2f(x1);
      float gg = part[0][4 + sub][smg][uc] + part[1][4 + sub][smg][uc] + bf2f(x2);
      float go = part[0][6 + sub][smg][uc] + part[1][6 + sub][smg][uc] + bf2f(x3);
      cc = sigmoid_f(gf) * cc + sigmoid_f(gi) * tanh_f(gg);
      float hh = sigmoid_f(go) * tanh_f(cc);
      uint16_t hb = f2bf(hh);
      unsigned int o = (unsigned int)__shfl_xor((int)(unsigned int)hb, 1);
      if ((u & 1) == 0) {
        uint32_t pk = (uint32_t)hb | (o << 16);
        const int b = gs0 + smg;
        uint32_t* hp = hbuf + (size_t)(1 - par) * (B_ * H_ / 2)
                            + ((size_t)b * H_ + U0 + u) / 2;
        __hip_atomic_store(hp, pk, __ATOMIC_RELAXED, __HIP_MEMORY_SCOPE_SYSTEM);
        if (sall || (t0 + tl == T_ - 1)) {
          uint32_t* sq = (uint32_t*)seq + (((size_t)b * T_ + (t0 + tl)) * H_ + U0 + u) / 2;
          *sq = pk;
        }
      }
      if (tl + 1 < TC_) {
        const uint16_t* p = xp + ((size_t)(gs0 + smg) * TC_ + tl + 1) * G4_ + U0 + u;
        x0 = p[0]; x1 = p[1024]; x2 = p[2048]; x3 = p[3072];
      }
    }
    __syncthreads();   // B: drains vmcnt -> h stores MALL-visible
    if (tid == 0)
      __hip_atomic_store(gflag + s5, (unsigned)(tl + 1),
                         __ATOMIC_RELAXED, __HIP_MEMORY_SCOPE_SYSTEM);
    if (tl + 1 < TC_) {
      stage_fused(tl + 1);
      __syncthreads();   // C
    }
  }
  if (tid < 512) cbuf[(size_t)(gs0 + smg) * H_ + U0 + u] = cc;
}

// ---------------- kernels ----------------
__global__ __launch_bounds__(1024, 2) void k_gemm(
    const void* A, int Adt, const uint16_t* __restrict__ W,
    const float* __restrict__ bias, uint16_t* __restrict__ xp, int K, int t0)
{
  __shared__ __align__(16) char SM[34816];
  gemm_body(blockIdx.x, threadIdx.x, SM, A, Adt, W, bias, xp, K, t0);
}

// Fused: blocks 0..255 = lstm(li,c); blocks 256..256+ngemm-1 = gemm(next chunk).
// gemm blocks never spin -> no co-residency requirement beyond lstm's own
// (gemm blocks retire and lstm blocks backfill; worst case = serial order).
__global__ __launch_bounds__(1024, 2) void k_fused(
    const uint16_t* __restrict__ whhf, const uint16_t* __restrict__ xp_cur,
    uint16_t* __restrict__ seq, uint32_t* __restrict__ hbuf,
    float* __restrict__ cbuf, unsigned int* __restrict__ flags, int t0, int sall,
    const void* gA, int Adt, const uint16_t* __restrict__ gW,
    const float* __restrict__ gbias, uint16_t* __restrict__ xp_nxt,
    int gK, int gt0, int ngemm)
{
  __shared__ __align__(16) char SM[50176];
  const int bid = blockIdx.x;
  if (bid < 256) {
    lstm_body(bid, threadIdx.x, SM, whhf, xp_cur, seq, hbuf, cbuf, flags, t0, sall);
  } else if (bid - 256 < ngemm) {
    gemm_body(bid - 256, threadIdx.x, SM, gA, Adt, gW, gbias, xp_nxt, gK, gt0);
  }
}

// ---------------- MLP head ----------------
__global__ __launch_bounds__(256) void k_mlp(
    const uint16_t* __restrict__ seq2,
    const float* __restrict__ w1, const float* __restrict__ b1,
    const float* __restrict__ w2, const float* __restrict__ b2,
    float* __restrict__ out)
{
  __shared__ float hv[H_];
  __shared__ float part[32][8];
  __shared__ float hid[32];
  const int b = blockIdx.x, tid = threadIdx.x;
  const uint16_t* hrow = seq2 + ((size_t)b * T_ + (T_ - 1)) * H_;
  for (int i = tid; i < H_; i += 256) hv[i] = bf2f(hrow[i]);
  __syncthreads();
  const int j = tid >> 3, p = tid & 7;
  float sum = 0.f;
  const float* wr = w1 + (size_t)j * H_ + p * 128;
  const float* hp = hv + p * 128;
  for (int k = 0; k < 128; ++k) sum += wr[k] * hp[k];
  part[j][p] = sum;
  __syncthreads();
  if (tid < 32) {
    float s2 = 0.f;
    #pragma unroll
    for (int pp = 0; pp < 8; ++pp) s2 += part[tid][pp];
    hid[tid] = fmaxf(s2 + b1[tid], 0.f);
  }
  __syncthreads();
  if (tid < 10) {
    float o = b2[tid];
    #pragma unroll
    for (int jj = 0; jj < 32; ++jj) o += hid[jj] * w2[tid * 32 + jj];
    out[b * 10 + tid] = o;
  }
}

// ---------------- launch ----------------
extern "C" void kernel_launch(void* const* d_in, const int* in_sizes, int n_in,
                              void* d_out, int out_size, void* d_ws, size_t ws_size,
                              hipStream_t stream)
{
  const float* x = (const float*)d_in[0];
  const float* w_ih[3] = {(const float*)d_in[1], (const float*)d_in[5], (const float*)d_in[9]};
  const float* w_hh[3] = {(const float*)d_in[2], (const float*)d_in[6], (const float*)d_in[10]};
  const float* b_ih[3] = {(const float*)d_in[3], (const float*)d_in[7], (const float*)d_in[11]};
  const float* b_hh[3] = {(const float*)d_in[4], (const float*)d_in[8], (const float*)d_in[12]};
  const float* w1 = (const float*)d_in[13];
  const float* b1 = (const float*)d_in[14];
  const float* w2 = (const float*)d_in[15];
  const float* b2 = (const float*)d_in[16];
  float* out = (float*)d_out;

  char* ws = (char*)d_ws;
  size_t off = 0;
  auto alloc = [&](size_t bytes) {
    char* p = ws + off;
    off += (bytes + 255) & ~(size_t)255;
    return p;
  };
  uint16_t* WIH0 = (uint16_t*)alloc((size_t)G4_ * IN_ * 2);
  uint16_t* WIH1 = (uint16_t*)alloc((size_t)G4_ * H_ * 2);
  uint16_t* WIH2 = (uint16_t*)alloc((size_t)G4_ * H_ * 2);
  float*    BIAS = (float*)alloc((size_t)3 * G4_ * 4);
  uint16_t* WHHF = (uint16_t*)alloc((size_t)3 * G4_ * H_ * 2);
  uint16_t* XPA  = (uint16_t*)alloc((size_t)B_ * TC_ * G4_ * 2);
  uint16_t* SEQ  = (uint16_t*)alloc((size_t)B_ * T_ * H_ * 2);
  uint32_t* HBUF = (uint32_t*)alloc((size_t)2 * B_ * H_ * 2);
  float*    CBUF = (float*)alloc((size_t)B_ * H_ * 4);
  unsigned int* FLG = (unsigned int*)alloc((size_t)12 * 1024 * 4);
  const size_t need_pipe = off + (size_t)B_ * TC_ * G4_ * 2 + 4096;
  const bool pipe = (ws_size >= need_pipe);
  uint16_t* XPB = pipe ? (uint16_t*)alloc((size_t)B_ * TC_ * G4_ * 2) : XPA;

  hipMemsetAsync(FLG, 0, (size_t)12 * 1024 * 4, stream);

  int n = G4_ * IN_;
  k_f32_to_bf16<<<n / 4 / 256, 256, 0, stream>>>(w_ih[0], WIH0, n);
  n = G4_ * H_;
  k_f32_to_bf16<<<n / 4 / 256, 256, 0, stream>>>(w_ih[1], WIH1, n);
  k_f32_to_bf16<<<n / 4 / 256, 256, 0, stream>>>(w_ih[2], WIH2, n);
  for (int li = 0; li < 3; ++li)
    k_bias<<<16, 256, 0, stream>>>(b_ih[li], b_hh[li], BIAS + li * G4_);
  for (int li = 0; li < 3; ++li)
    k_whh_frag<<<2048, 256, 0, stream>>>(w_hh[li], WHHF + (size_t)li * G4_ * H_);

  const void* gAsrc[3] = {(const void*)x, (const void*)SEQ, (const void*)SEQ};
  const int   gAdt[3]  = {1, 0, 0};
  const uint16_t* gWw[3] = {WIH0, WIH1, WIH2};
  const int   gKk[3]   = {IN_, H_, H_};

  if (pipe) {
    hipMemsetAsync(HBUF, 0, (size_t)2 * B_ * H_ * 2, stream);
    hipMemsetAsync(CBUF, 0, (size_t)B_ * H_ * 4, stream);
    k_gemm<<<2048, 1024, 0, stream>>>(gAsrc[0], gAdt[0], gWw[0], BIAS, XPA, gKk[0], 0);
    uint16_t* xpb[2] = {XPA, XPB};
    for (int k = 0; k < 12; ++k) {
      const int li = k >> 2, c = k & 3;
      if (c == 0 && k > 0) {
        hipMemsetAsync(HBUF, 0, (size_t)2 * B_ * H_ * 2, stream);
        hipMemsetAsync(CBUF, 0, (size_t)B_ * H_ * 4, stream);
      }
      const int sall = (li == 2) ? 0 : 1;
      unsigned int* flg = FLG + (size_t)k * 1024;
      if (k < 11) {
        const int kn = k + 1, lj = kn >> 2, cj = kn & 3;
        k_fused<<<2304, 1024, 0, stream>>>(
            WHHF + (size_t)li * G4_ * H_, xpb[k & 1], SEQ, HBUF, CBUF, flg,
            c * TC_, sall,
            gAsrc[lj], gAdt[lj], gWw[lj], BIAS + lj * G4_, xpb[kn & 1],
            gKk[lj], cj * TC_, 2048);
      } else {
        k_fused<<<256, 1024, 0, stream>>>(
            WHHF + (size_t)li * G4_ * H_, xpb[k & 1], SEQ, HBUF, CBUF, flg,
            c * TC_, sall,
            nullptr, 0, nullptr, nullptr, nullptr, 0, 0, 0);
      }
    }
  } else {
    for (int k = 0; k < 12; ++k) {
      const int li = k >> 2, c = k & 3;
      if (c == 0) {
        hipMemsetAsync(HBUF, 0, (size_t)2 * B_ * H_ * 2, stream);
        hipMemsetAsync(CBUF, 0, (size_t)B_ * H_ * 4, stream);
      }
      const int sall = (li == 2) ? 0 : 1;
      unsigned int* flg = FLG + (size_t)k * 1024;
      k_gemm<<<2048, 1024, 0, stream>>>(gAsrc[li], gAdt[li], gWw[li],
                                        BIAS + li * G4_, XPA, gKk[li], c * TC_);
      k_fused<<<256, 1024, 0, stream>>>(
          WHHF + (size_t)li * G4_ * H_, XPA, SEQ, HBUF, CBUF, flg,
          c * TC_, sall,
          nullptr, 0, nullptr, nullptr, nullptr, 0, 0, 0);
    }
  }
  k_mlp<<<B_, 256, 0, stream>>>(SEQ, w1, b1, w2, b2, out);
}

// Round 17
// 3370.634 us; speedup vs baseline: 1.2729x; 1.2729x over previous
//
#include <hip/hip_runtime.h>
#include <hip/hip_bf16.h>
#include <stdint.h>

#define B_ 128
#define T_ 256
#define IN_ 512
#define H_ 1024
#define G4_ 4096
#define TC_ 64              // time chunk
#define NCHUNK_ (T_ / TC_)

typedef __bf16 bf16x8 __attribute__((ext_vector_type(8)));
typedef float f32x4 __attribute__((ext_vector_type(4)));
typedef uint32_t u32x4 __attribute__((ext_vector_type(4)));

#define AS1U(p) ((const __attribute__((address_space(1))) unsigned int*)(p))
#define AS3U(p) ((__attribute__((address_space(3))) unsigned int*)(p))

__device__ __forceinline__ uint16_t f2bf(float f) {
  union { float f; uint32_t u; } v; v.f = f;
  uint32_t r = (v.u + 0x7fffu + ((v.u >> 16) & 1u)) >> 16;
  return (uint16_t)r;
}
__device__ __forceinline__ float bf2f(uint16_t h) {
  union { uint32_t u; float f; } v; v.u = ((uint32_t)h) << 16;
  return v.f;
}
__device__ __forceinline__ float sigmoid_f(float x) {
  return 1.f / (1.f + __expf(-x));
}
__device__ __forceinline__ float tanh_f(float x) {
  x = fminf(15.f, fmaxf(-15.f, x));
  float e = __expf(2.f * x);
  return (e - 1.f) / (e + 1.f);
}

// ---------------- prep kernels ----------------
__global__ void k_f32_to_bf16(const float* __restrict__ src, uint16_t* __restrict__ dst, int n) {
  int i = (blockIdx.x * blockDim.x + threadIdx.x) * 4;
  if (i >= n) return;
  float4 v = *(const float4*)(src + i);
  ushort4 o;
  o.x = f2bf(v.x); o.y = f2bf(v.y); o.z = f2bf(v.z); o.w = f2bf(v.w);
  *(ushort4*)(dst + i) = o;
}

__global__ void k_bias(const float* __restrict__ a, const float* __restrict__ b, float* __restrict__ o) {
  int i = blockIdx.x * blockDim.x + threadIdx.x;
  if (i < G4_) o[i] = a[i] + b[i];
}

// Rearrange w_hh (fp32 [4096][1024]) into per-(slice,wave) MFMA B-fragments, bf16.
__global__ void k_whh_frag(const float* __restrict__ whh, uint16_t* __restrict__ dst) {
  int t = blockIdx.x * blockDim.x + threadIdx.x;   // 0..524287
  int lane = t & 63;
  int kk = (t >> 6) & 15;
  int w  = (t >> 10) & 15;
  int s5 = t >> 14;
  int nt = w & 7, kh = w >> 3;
  int row = (nt >> 1) * 1024 + s5 * 32 + (nt & 1) * 16 + (lane & 15);
  int col = kh * 512 + kk * 32 + ((lane >> 4) << 3);
  const float* sp = whh + (size_t)row * H_ + col;
  uint16_t o[8];
  #pragma unroll
  for (int j = 0; j < 8; ++j) o[j] = f2bf(sp[j]);
  uint4 pk;
  __builtin_memcpy(&pk, o, 16);
  *(uint4*)(dst + (size_t)t * 8) = pk;
}

// ---------------- input-projection GEMM ----------------
// LDS-staged coalesced C epilogue; Cs ALIASES As/Bs (disjoint lifetimes,
// separated by a barrier) -> 34.8KB LDS -> 4 blocks/CU.
// Adt==1: A is f32 (the raw x input); staging converts inline (no XBF pass).
__global__ __launch_bounds__(256, 1) void k_gemm_xp(
    const void* __restrict__ A, int Adt, const uint16_t* __restrict__ W,
    const float* __restrict__ bias, uint16_t* __restrict__ xp,
    int K, int t0)
{
  __shared__ __align__(16) char smem[128 * 136 * 2];   // 34816 B
  uint16_t* As = (uint16_t*)smem;                      // [128*32] 8KB (K loop)
  uint16_t* Bs = (uint16_t*)(smem + 16384);            // 8KB
  uint16_t* Cs = (uint16_t*)smem;                      // [128][136] (epilogue)
  const int tid = threadIdx.x;
  const int l = tid & 63;
  const int w = tid >> 6;
  const int mx = blockIdx.x;
  const int n0 = blockIdx.y * 128;
  const int wm = (w >> 1) * 64;
  const int wn = (w & 1) * 64;

  f32x4 acc[4][4] = {};

  for (int k0 = 0; k0 < K; k0 += 32) {
    __syncthreads();
    #pragma unroll
    for (int it = 0; it < 2; ++it) {
      const int chunk = w * 2 + it;
      const int loff = chunk * 1024 + l * 16;  // byte offset in tile
      const int row = loff >> 6;               // 0..127
      const int colb = loff & 63;
      const int gm = mx * 512 + t0 + ((row >> 6) << 8) + (row & 63);
      if (Adt == 0) {
        const uint16_t* ga = (const uint16_t*)A + (size_t)gm * K + k0 + (colb >> 1);
        __builtin_amdgcn_global_load_lds(AS1U(ga), AS3U((char*)As + loff), 16, 0, 0);
      } else {
        const float* sp = (const float*)A + (size_t)gm * K + k0 + (colb >> 1);
        float4 v0 = *(const float4*)sp;
        float4 v1 = *(const float4*)(sp + 4);
        uint16_t o[8] = {f2bf(v0.x), f2bf(v0.y), f2bf(v0.z), f2bf(v0.w),
                         f2bf(v1.x), f2bf(v1.y), f2bf(v1.z), f2bf(v1.w)};
        uint4 pk; __builtin_memcpy(&pk, o, 16);
        *(uint4*)((char*)As + loff) = pk;
      }
      const uint16_t* gb = W + (size_t)(n0 + row) * K + k0 + (colb >> 1);
      __builtin_amdgcn_global_load_lds(AS1U(gb), AS3U((char*)Bs + loff), 16, 0, 0);
    }
    __syncthreads();
    bf16x8 af[4], bfr[4];
    #pragma unroll
    for (int i = 0; i < 4; ++i)
      af[i] = *(const bf16x8*)&As[(wm + i * 16 + (l & 15)) * 32 + ((l >> 4) << 3)];
    #pragma unroll
    for (int j = 0; j < 4; ++j)
      bfr[j] = *(const bf16x8*)&Bs[(wn + j * 16 + (l & 15)) * 32 + ((l >> 4) << 3)];
    #pragma unroll
    for (int i = 0; i < 4; ++i) {
      #pragma unroll
      for (int j = 0; j < 4; ++j)
        acc[i][j] = __builtin_amdgcn_mfma_f32_16x16x32_bf16(af[i], bfr[j], acc[i][j], 0, 0, 0);
    }
  }
  __syncthreads();   // all fragment reads done -> safe to overwrite As/Bs as Cs

  // stage (acc + bias) -> bf16 into Cs (wave-exclusive subtile)
  #pragma unroll
  for (int i = 0; i < 4; ++i) {
    const int row = wm + i * 16 + ((l >> 4) << 2);
    #pragma unroll
    for (int j = 0; j < 4; ++j) {
      const int col = wn + j * 16 + (l & 15);
      const float bv = bias[n0 + col];
      #pragma unroll
      for (int r = 0; r < 4; ++r)
        Cs[(row + r) * 136 + col] = f2bf(acc[i][j][r] + bv);
    }
  }
  __syncthreads();
  // coalesced store: lane l -> row it*16 + w*4 + (l>>4), cols (l&15)*8..+7
  #pragma unroll
  for (int it = 0; it < 8; ++it) {
    const int row = it * 16 + w * 4 + (l >> 4);
    uint4 v = *(const uint4*)&Cs[row * 136 + (l & 15) * 8];
    *(uint4*)(xp + (size_t)(mx * 128 + row) * G4_ + n0 + (l & 15) * 8) = v;
  }
}

// ---------------- persistent LSTM recurrence ----------------
// Round-11 protocol verbatim (measured optimum: 203-207us, 3.2us/step):
// 256 blocks x 1024 thr; 8 groups (g=bid&7) x 16 samples; 32 blocks/group;
// w_hh fragments resident in VGPRs; h via SYSTEM-scope write-through;
// per-slice flags (32/group, one 128B line) published by tid0 after barrier-B
// drain; FUSED poll+stage clause [flag; 32B data] post-barrier; swizzled Astg
// (conflict-free stage write + mfma read); 3 barriers/step.
__global__ __launch_bounds__(1024, 4) void k_lstm(
    const uint16_t* __restrict__ whhf, const uint16_t* __restrict__ xp,
    uint16_t* __restrict__ seq, uint32_t* __restrict__ hbuf,
    float* __restrict__ cbuf, unsigned int* __restrict__ flags, int t0, int sall)
{
  __shared__ __align__(16) uint16_t Astg[2048 * 8];     // 32 KiB swizzled slots
  __shared__ float part[2][8][16][17];                  // 17.4 KiB
  const int tid = threadIdx.x;
  const int l = tid & 63;
  const int w = tid >> 6;           // 0..15: stage row; mfma: nt=w&7, kh=w>>3
  const int nt = w & 7;
  const int kh = w >> 3;
  const int bid = blockIdx.x;
  const int g = bid & 7;
  const int s5 = bid >> 3;          // 0..31
  const int U0 = s5 * 32;
  const int gs0 = g * 16;

  unsigned int* gflag = flags + g * 32;

  // resident weight fragments (64 VGPR/lane)
  bf16x8 bfr[16];
  {
    const uint16_t* wp = whhf + (size_t)(s5 * 16 + w) * 8192 + l * 8;
    #pragma unroll
    for (int kk = 0; kk < 16; ++kk)
      bfr[kk] = *(const bf16x8*)(wp + kk * 512);
  }

  const int u = tid & 31;
  const int smg = (tid >> 5) & 15;
  float cc = 0.f;
  if (tid < 512) cc = cbuf[(size_t)(gs0 + smg) * H_ + U0 + u];

  uint16_t x0 = 0, x1 = 0, x2 = 0, x3 = 0;
  if (tid < 512) {
    const uint16_t* p = xp + ((size_t)(gs0 + smg) * TC_ + 0) * G4_ + U0 + u;
    x0 = p[0]; x1 = p[1024]; x2 = p[2048]; x3 = p[3072];
  }

  // fused poll+stage of state tl: wave w = sample row gs0+w, lane l = 32B at
  // col l*32 (units 16l..16l+15, produced by slice l>>1). Per-lane validated
  // retry; first try succeeds in steady state -> stage costs ~1 MALL RTT.
  auto stage_fused = [&](int tl) {
    const int par = tl & 1;
    const unsigned tgt = (unsigned)tl;   // chunk-local state index
    const char* src = (const char*)hbuf + (size_t)par * (B_ * H_ * 2)
                      + (size_t)(gs0 + w) * 2048 + (size_t)l * 32;
    const unsigned int* fp = gflag + (l >> 1);
    u32x4 q0, q1;
    unsigned fv;
    do {
      asm volatile(
        "global_load_dword %0, %3, off sc0 sc1\n\t"
        "global_load_dwordx4 %1, %4, off sc0 sc1\n\t"
        "global_load_dwordx4 %2, %4, off offset:16 sc0 sc1\n\t"
        "s_waitcnt vmcnt(0)"
        : "=&v"(fv), "=&v"(q0), "=&v"(q1)
        : "v"(fp), "v"(src)
        : "memory");
      if (fv >= tgt) break;
      __builtin_amdgcn_s_sleep(1);
    } while (true);
    const int base = 512 * l + ((w ^ (l & 7)) << 4);
    *(u32x4*)((char*)Astg + base) = q0;
    *(u32x4*)((char*)Astg + base + 256) = q1;
  };

  stage_fused(0);    // flags start at 0 == tgt -> no spin; hbuf memset fresh
  __syncthreads();

  for (int tl = 0; tl < TC_; ++tl) {
    const int par = tl & 1;

    // ---- MFMA phase: swizzled ds_read_b128 (conflict-free), B resident ----
    f32x4 e0 = {0.f, 0.f, 0.f, 0.f};
    f32x4 e1 = {0.f, 0.f, 0.f, 0.f};
    #pragma unroll
    for (int kk = 0; kk < 16; kk += 2) {
      const int c0 = kh * 64 + kk * 4 + (l >> 4);
      const int c1 = c0 + 4;
      const int sw0 = (l & 15) ^ ((2 * kk + (l >> 5)) & 7);
      const int sw1 = (l & 15) ^ ((2 * (kk + 1) + (l >> 5)) & 7);
      bf16x8 a0 = *(const bf16x8*)((const char*)Astg + ((size_t)(c0 * 16 + sw0) << 4));
      bf16x8 a1 = *(const bf16x8*)((const char*)Astg + ((size_t)(c1 * 16 + sw1) << 4));
      e0 = __builtin_amdgcn_mfma_f32_16x16x32_bf16(a0, bfr[kk],     e0, 0, 0, 0);
      e1 = __builtin_amdgcn_mfma_f32_16x16x32_bf16(a1, bfr[kk + 1], e1, 0, 0, 0);
    }
    f32x4 e = e0 + e1;
    #pragma unroll
    for (int r = 0; r < 4; ++r)
      part[kh][nt][((l >> 4) << 2) + r][l & 15] = e[r];
    __syncthreads();   // A: part visible; all Astg reads complete

    // ---- gate phase (waves 0..7) ----
    if (tid < 512) {
      const int sub = u >> 4, uc = u & 15;
      float gi = part[0][0 + sub][smg][uc] + part[1][0 + sub][smg][uc] + bf2f(x0);
      float gf = part[0][2 + sub][smg][uc] + part[1][2 + sub][smg][uc] + bf2f(x1);
      float gg = part[0][4 + sub][smg][uc] + part[1][4 + sub][smg][uc] + bf2f(x2);
      float go = part[0][6 + sub][smg][uc] + part[1][6 + sub][smg][uc] + bf2f(x3);
      cc = sigmoid_f(gf) * cc + sigmoid_f(gi) * tanh_f(gg);
      float hh = sigmoid_f(go) * tanh_f(cc);
      uint16_t hb = f2bf(hh);
      unsigned int o = (unsigned int)__shfl_xor((int)(unsigned int)hb, 1);
      if ((u & 1) == 0) {
        uint32_t pk = (uint32_t)hb | (o << 16);
        const int b = gs0 + smg;
        uint32_t* hp = hbuf + (size_t)(1 - par) * (B_ * H_ / 2)
                            + ((size_t)b * H_ + U0 + u) / 2;
        __hip_atomic_store(hp, pk, __ATOMIC_RELAXED, __HIP_MEMORY_SCOPE_SYSTEM);
        if (sall || (t0 + tl == T_ - 1)) {
          uint32_t* sq = (uint32_t*)seq + (((size_t)b * T_ + (t0 + tl)) * H_ + U0 + u) / 2;
          *sq = pk;
        }
      }
      if (tl + 1 < TC_) {   // xp prefetch after h-store issue
        const uint16_t* p = xp + ((size_t)(gs0 + smg) * TC_ + tl + 1) * G4_ + U0 + u;
        x0 = p[0]; x1 = p[1024]; x2 = p[2048]; x3 = p[3072];
      }
    }
    __syncthreads();   // B: drains vmcnt -> h stores MALL-visible
    if (tid == 0)
      __hip_atomic_store(gflag + s5, (unsigned)(tl + 1),
                         __ATOMIC_RELAXED, __HIP_MEMORY_SCOPE_SYSTEM);
    if (tl + 1 < TC_) {
      stage_fused(tl + 1);   // fused poll+load+swizzled LDS write
      __syncthreads();       // C: Astg ready for next MFMA
    }
  }
  if (tid < 512) cbuf[(size_t)(gs0 + smg) * H_ + U0 + u] = cc;
}

// ---------------- MLP head ----------------
__global__ __launch_bounds__(256) void k_mlp(
    const uint16_t* __restrict__ seq2,
    const float* __restrict__ w1, const float* __restrict__ b1,
    const float* __restrict__ w2, const float* __restrict__ b2,
    float* __restrict__ out)
{
  __shared__ float hv[H_];
  __shared__ float part[32][8];
  __shared__ float hid[32];
  const int b = blockIdx.x, tid = threadIdx.x;
  const uint16_t* hrow = seq2 + ((size_t)b * T_ + (T_ - 1)) * H_;
  for (int i = tid; i < H_; i += 256) hv[i] = bf2f(hrow[i]);
  __syncthreads();
  const int j = tid >> 3, p = tid & 7;
  float sum = 0.f;
  const float* wr = w1 + (size_t)j * H_ + p * 128;
  const float* hp = hv + p * 128;
  for (int k = 0; k < 128; ++k) sum += wr[k] * hp[k];
  part[j][p] = sum;
  __syncthreads();
  if (tid < 32) {
    float s2 = 0.f;
    #pragma unroll
    for (int pp = 0; pp < 8; ++pp) s2 += part[tid][pp];
    hid[tid] = fmaxf(s2 + b1[tid], 0.f);
  }
  __syncthreads();
  if (tid < 10) {
    float o = b2[tid];
    #pragma unroll
    for (int jj = 0; jj < 32; ++jj) o += hid[jj] * w2[tid * 32 + jj];
    out[b * 10 + tid] = o;
  }
}

// ---------------- launch ----------------
extern "C" void kernel_launch(void* const* d_in, const int* in_sizes, int n_in,
                              void* d_out, int out_size, void* d_ws, size_t ws_size,
                              hipStream_t stream)
{
  const float* x = (const float*)d_in[0];
  const float* w_ih[3] = {(const float*)d_in[1], (const float*)d_in[5], (const float*)d_in[9]};
  const float* w_hh[3] = {(const float*)d_in[2], (const float*)d_in[6], (const float*)d_in[10]};
  const float* b_ih[3] = {(const float*)d_in[3], (const float*)d_in[7], (const float*)d_in[11]};
  const float* b_hh[3] = {(const float*)d_in[4], (const float*)d_in[8], (const float*)d_in[12]};
  const float* w1 = (const float*)d_in[13];
  const float* b1 = (const float*)d_in[14];
  const float* w2 = (const float*)d_in[15];
  const float* b2 = (const float*)d_in[16];
  float* out = (float*)d_out;

  char* ws = (char*)d_ws;
  size_t off = 0;
  auto alloc = [&](size_t bytes) {
    char* p = ws + off;
    off += (bytes + 255) & ~(size_t)255;
    return p;
  };
  uint16_t* WIH0 = (uint16_t*)alloc((size_t)G4_ * IN_ * 2);
  uint16_t* WIH1 = (uint16_t*)alloc((size_t)G4_ * H_ * 2);
  uint16_t* WIH2 = (uint16_t*)alloc((size_t)G4_ * H_ * 2);
  float*    BIAS = (float*)alloc((size_t)3 * G4_ * 4);
  uint16_t* WHHF = (uint16_t*)alloc((size_t)3 * G4_ * H_ * 2);
  uint16_t* XP   = (uint16_t*)alloc((size_t)B_ * TC_ * G4_ * 2);
  uint16_t* SEQ  = (uint16_t*)alloc((size_t)B_ * T_ * H_ * 2);
  uint32_t* HBUF = (uint32_t*)alloc((size_t)2 * B_ * H_ * 2);
  float*    CBUF = (float*)alloc((size_t)B_ * H_ * 4);
  unsigned int* FLG = (unsigned int*)alloc((size_t)3 * NCHUNK_ * 1024 * 4);

  hipMemsetAsync(FLG, 0, (size_t)3 * NCHUNK_ * 1024 * 4, stream);

  int n = G4_ * IN_;
  k_f32_to_bf16<<<n / 4 / 256, 256, 0, stream>>>(w_ih[0], WIH0, n);
  n = G4_ * H_;
  k_f32_to_bf16<<<n / 4 / 256, 256, 0, stream>>>(w_ih[1], WIH1, n);
  k_f32_to_bf16<<<n / 4 / 256, 256, 0, stream>>>(w_ih[2], WIH2, n);
  for (int li = 0; li < 3; ++li)
    k_bias<<<16, 256, 0, stream>>>(b_ih[li], b_hh[li], BIAS + li * G4_);
  for (int li = 0; li < 3; ++li)
    k_whh_frag<<<2048, 256, 0, stream>>>(w_hh[li], WHHF + (size_t)li * G4_ * H_);

  const void* seq_in[3] = {(const void*)x, (const void*)SEQ, (const void*)SEQ};
  const int   adt[3]    = {1, 0, 0};
  const uint16_t* wih[3] = {WIH0, WIH1, WIH2};
  const int Ks[3] = {IN_, H_, H_};

  for (int li = 0; li < 3; ++li) {
    hipMemsetAsync(HBUF, 0, (size_t)2 * B_ * H_ * 2, stream);
    hipMemsetAsync(CBUF, 0, (size_t)B_ * H_ * 4, stream);
    const int sall = (li == 2) ? 0 : 1;
    for (int c = 0; c < NCHUNK_; ++c) {
      dim3 grid(64, 32);
      k_gemm_xp<<<grid, 256, 0, stream>>>(seq_in[li], adt[li], wih[li],
                                          BIAS + li * G4_, XP, Ks[li], c * TC_);
      unsigned int* flg_lc = FLG + (size_t)(li * NCHUNK_ + c) * 1024;
      k_lstm<<<256, 1024, 0, stream>>>(WHHF + (size_t)li * G4_ * H_, XP, SEQ, HBUF,
                                       CBUF, flg_lc, c * TC_, sall);
    }
  }
  k_mlp<<<B_, 256, 0, stream>>>(SEQ, w1, b1, w2, b2, out);
}

// Round 18
// 3279.550 us; speedup vs baseline: 1.3083x; 1.0278x over previous
//
#include <hip/hip_runtime.h>
#include <hip/hip_bf16.h>
#include <stdint.h>

#define B_ 128
#define T_ 256
#define IN_ 512
#define H_ 1024
#define G4_ 4096
#define TC_ 64              // time chunk
#define NCHUNK_ (T_ / TC_)

typedef __bf16 bf16x8 __attribute__((ext_vector_type(8)));
typedef float f32x4 __attribute__((ext_vector_type(4)));
typedef uint32_t u32x4 __attribute__((ext_vector_type(4)));

#define AS1U(p) ((const __attribute__((address_space(1))) unsigned int*)(p))
#define AS3U(p) ((__attribute__((address_space(3))) unsigned int*)(p))

__device__ __forceinline__ uint16_t f2bf(float f) {
  union { float f; uint32_t u; } v; v.f = f;
  uint32_t r = (v.u + 0x7fffu + ((v.u >> 16) & 1u)) >> 16;
  return (uint16_t)r;
}
__device__ __forceinline__ float bf2f(uint16_t h) {
  union { uint32_t u; float f; } v; v.u = ((uint32_t)h) << 16;
  return v.f;
}
__device__ __forceinline__ float sigmoid_f(float x) {
  return 1.f / (1.f + __expf(-x));
}
__device__ __forceinline__ float tanh_f(float x) {
  x = fminf(15.f, fmaxf(-15.f, x));
  float e = __expf(2.f * x);
  return (e - 1.f) / (e + 1.f);
}

// ---------------- prep kernels ----------------
__global__ void k_f32_to_bf16(const float* __restrict__ src, uint16_t* __restrict__ dst, int n) {
  int i = (blockIdx.x * blockDim.x + threadIdx.x) * 4;
  if (i >= n) return;
  float4 v = *(const float4*)(src + i);
  ushort4 o;
  o.x = f2bf(v.x); o.y = f2bf(v.y); o.z = f2bf(v.z); o.w = f2bf(v.w);
  *(ushort4*)(dst + i) = o;
}

__global__ void k_bias(const float* __restrict__ a, const float* __restrict__ b, float* __restrict__ o) {
  int i = blockIdx.x * blockDim.x + threadIdx.x;
  if (i < G4_) o[i] = a[i] + b[i];
}

// Rearrange w_hh (fp32 [4096][1024]) into per-(slice,wave) MFMA B-fragments, bf16.
__global__ void k_whh_frag(const float* __restrict__ whh, uint16_t* __restrict__ dst) {
  int t = blockIdx.x * blockDim.x + threadIdx.x;   // 0..524287
  int lane = t & 63;
  int kk = (t >> 6) & 15;
  int w  = (t >> 10) & 15;
  int s5 = t >> 14;
  int nt = w & 7, kh = w >> 3;
  int row = (nt >> 1) * 1024 + s5 * 32 + (nt & 1) * 16 + (lane & 15);
  int col = kh * 512 + kk * 32 + ((lane >> 4) << 3);
  const float* sp = whh + (size_t)row * H_ + col;
  uint16_t o[8];
  #pragma unroll
  for (int j = 0; j < 8; ++j) o[j] = f2bf(sp[j]);
  uint4 pk;
  __builtin_memcpy(&pk, o, 16);
  *(uint4*)(dst + (size_t)t * 8) = pk;
}

// Rearrange w_ih (fp32 [4096][K]) into MFMA-fragment order for the gemm:
// dst[((nt*(K/32) + kc)*8 + j2)*512 + lane*8 + e] =
//   bf16(w_ih[nt*128 + j2*16 + (lane&15)][kc*32 + (lane>>4)*8 + e])
// -> staging is linear 8KB/(ntile,kc) and fragment ds_read_b128 is lane-linear
//    (conflict-free: 64 lanes span 1024 contiguous bytes).
__global__ void k_wih_frag(const float* __restrict__ wih, uint16_t* __restrict__ dst, int K) {
  int t = blockIdx.x * blockDim.x + threadIdx.x;   // 4096*K/8 threads
  int lane = t & 63;
  int j2 = (t >> 6) & 7;
  int kcq = t >> 9;
  int nkc = K >> 5;
  int kc = kcq % nkc;
  int nt = kcq / nkc;
  int row = nt * 128 + j2 * 16 + (lane & 15);
  int col = kc * 32 + ((lane >> 4) << 3);
  const float* sp = wih + (size_t)row * K + col;
  uint16_t o[8];
  #pragma unroll
  for (int j = 0; j < 8; ++j) o[j] = f2bf(sp[j]);
  uint4 pk;
  __builtin_memcpy(&pk, o, 16);
  *(uint4*)(dst + (size_t)t * 8) = pk;
}

// ---------------- input-projection GEMM ----------------
// LDS-staged coalesced C epilogue; Cs ALIASES As/Bs (disjoint lifetimes) ->
// 34.8KB LDS -> 4 blocks/CU. B (w_ih) is pre-arranged in fragment order:
// staging = linear global_load_lds; fragment read = lane-linear (conflict-free).
__global__ __launch_bounds__(256, 1) void k_gemm_xp(
    const uint16_t* __restrict__ A, const uint16_t* __restrict__ WF,
    const float* __restrict__ bias, uint16_t* __restrict__ xp,
    int K, int t0)
{
  __shared__ __align__(16) char smem[128 * 136 * 2];   // 34816 B
  uint16_t* As = (uint16_t*)smem;                      // 8KB (K loop)
  uint16_t* Bs = (uint16_t*)(smem + 16384);            // 8KB fragment-order
  uint16_t* Cs = (uint16_t*)smem;                      // [128][136] epilogue
  const int tid = threadIdx.x;
  const int l = tid & 63;
  const int w = tid >> 6;
  const int mx = blockIdx.x;
  const int n0 = blockIdx.y * 128;
  const int wm = (w >> 1) * 64;
  const int wn = (w & 1) * 64;
  const int nkc = K >> 5;

  f32x4 acc[4][4] = {};

  for (int k0 = 0; k0 < K; k0 += 32) {
    __syncthreads();
    // A tile: 8KB, row-major [128][32]
    #pragma unroll
    for (int it = 0; it < 2; ++it) {
      const int chunk = w * 2 + it;
      const int loff = chunk * 1024 + l * 16;  // byte offset in tile
      const int row = loff >> 6;               // 0..127
      const int colb = loff & 63;
      const int gm = mx * 512 + t0 + ((row >> 6) << 8) + (row & 63);
      const uint16_t* ga = A + (size_t)gm * K + k0 + (colb >> 1);
      __builtin_amdgcn_global_load_lds(AS1U(ga), AS3U((char*)As + loff), 16, 0, 0);
    }
    // B tile: 8KB contiguous fragment-order chunk for (ntile=blockIdx.y, kc)
    {
      const uint16_t* gb = WF + (((size_t)blockIdx.y * nkc + (k0 >> 5)) << 12);
      #pragma unroll
      for (int rr = 0; rr < 2; ++rr) {
        const int boff = rr * 4096 + w * 1024 + l * 16;
        __builtin_amdgcn_global_load_lds(AS1U(gb + boff / 2),
                                         AS3U((char*)Bs + boff), 16, 0, 0);
      }
    }
    __syncthreads();
    bf16x8 af[4], bfr[4];
    #pragma unroll
    for (int i = 0; i < 4; ++i)
      af[i] = *(const bf16x8*)&As[(wm + i * 16 + (l & 15)) * 32 + ((l >> 4) << 3)];
    #pragma unroll
    for (int j = 0; j < 4; ++j)
      bfr[j] = *(const bf16x8*)&Bs[((((w & 1) * 4 + j) * 64) + l) * 8];
    #pragma unroll
    for (int i = 0; i < 4; ++i) {
      #pragma unroll
      for (int j = 0; j < 4; ++j)
        acc[i][j] = __builtin_amdgcn_mfma_f32_16x16x32_bf16(af[i], bfr[j], acc[i][j], 0, 0, 0);
    }
  }
  __syncthreads();   // all fragment reads done -> safe to overwrite As/Bs as Cs

  // stage (acc + bias) -> bf16 into Cs (wave-exclusive subtile)
  #pragma unroll
  for (int i = 0; i < 4; ++i) {
    const int row = wm + i * 16 + ((l >> 4) << 2);
    #pragma unroll
    for (int j = 0; j < 4; ++j) {
      const int col = wn + j * 16 + (l & 15);
      const float bv = bias[n0 + col];
      #pragma unroll
      for (int r = 0; r < 4; ++r)
        Cs[(row + r) * 136 + col] = f2bf(acc[i][j][r] + bv);
    }
  }
  __syncthreads();
  // coalesced store: lane l -> row it*16 + w*4 + (l>>4), cols (l&15)*8..+7
  #pragma unroll
  for (int it = 0; it < 8; ++it) {
    const int row = it * 16 + w * 4 + (l >> 4);
    uint4 v = *(const uint4*)&Cs[row * 136 + (l & 15) * 8];
    *(uint4*)(xp + (size_t)(mx * 128 + row) * G4_ + n0 + (l & 15) * 8) = v;
  }
}

// ---------------- persistent LSTM recurrence ----------------
// Round-11 protocol verbatim (measured optimum: 203-207us, 3.2us/step):
// 256 blocks x 1024 thr; 8 groups (g=bid&7) x 16 samples; 32 blocks/group;
// w_hh fragments resident in VGPRs; h via SYSTEM-scope write-through;
// per-slice flags (32/group, one 128B line) published by tid0 after barrier-B
// drain; FUSED poll+stage clause [flag; 32B data] post-barrier; swizzled Astg
// (conflict-free stage write + mfma read); 3 barriers/step.
__global__ __launch_bounds__(1024, 4) void k_lstm(
    const uint16_t* __restrict__ whhf, const uint16_t* __restrict__ xp,
    uint16_t* __restrict__ seq, uint32_t* __restrict__ hbuf,
    float* __restrict__ cbuf, unsigned int* __restrict__ flags, int t0, int sall)
{
  __shared__ __align__(16) uint16_t Astg[2048 * 8];     // 32 KiB swizzled slots
  __shared__ float part[2][8][16][17];                  // 17.4 KiB
  const int tid = threadIdx.x;
  const int l = tid & 63;
  const int w = tid >> 6;           // 0..15: stage row; mfma: nt=w&7, kh=w>>3
  const int nt = w & 7;
  const int kh = w >> 3;
  const int bid = blockIdx.x;
  const int g = bid & 7;
  const int s5 = bid >> 3;          // 0..31
  const int U0 = s5 * 32;
  const int gs0 = g * 16;

  unsigned int* gflag = flags + g * 32;

  // resident weight fragments (64 VGPR/lane)
  bf16x8 bfr[16];
  {
    const uint16_t* wp = whhf + (size_t)(s5 * 16 + w) * 8192 + l * 8;
    #pragma unroll
    for (int kk = 0; kk < 16; ++kk)
      bfr[kk] = *(const bf16x8*)(wp + kk * 512);
  }

  const int u = tid & 31;
  const int smg = (tid >> 5) & 15;
  float cc = 0.f;
  if (tid < 512) cc = cbuf[(size_t)(gs0 + smg) * H_ + U0 + u];

  uint16_t x0 = 0, x1 = 0, x2 = 0, x3 = 0;
  if (tid < 512) {
    const uint16_t* p = xp + ((size_t)(gs0 + smg) * TC_ + 0) * G4_ + U0 + u;
    x0 = p[0]; x1 = p[1024]; x2 = p[2048]; x3 = p[3072];
  }

  // fused poll+stage of state tl: wave w = sample row gs0+w, lane l = 32B at
  // col l*32 (units 16l..16l+15, produced by slice l>>1). Per-lane validated
  // retry; first try succeeds in steady state -> stage costs ~1 MALL RTT.
  auto stage_fused = [&](int tl) {
    const int par = tl & 1;
    const unsigned tgt = (unsigned)tl;   // chunk-local state index
    const char* src = (const char*)hbuf + (size_t)par * (B_ * H_ * 2)
                      + (size_t)(gs0 + w) * 2048 + (size_t)l * 32;
    const unsigned int* fp = gflag + (l >> 1);
    u32x4 q0, q1;
    unsigned fv;
    do {
      asm volatile(
        "global_load_dword %0, %3, off sc0 sc1\n\t"
        "global_load_dwordx4 %1, %4, off sc0 sc1\n\t"
        "global_load_dwordx4 %2, %4, off offset:16 sc0 sc1\n\t"
        "s_waitcnt vmcnt(0)"
        : "=&v"(fv), "=&v"(q0), "=&v"(q1)
        : "v"(fp), "v"(src)
        : "memory");
      if (fv >= tgt) break;
      __builtin_amdgcn_s_sleep(1);
    } while (true);
    const int base = 512 * l + ((w ^ (l & 7)) << 4);
    *(u32x4*)((char*)Astg + base) = q0;
    *(u32x4*)((char*)Astg + base + 256) = q1;
  };

  stage_fused(0);    // flags start at 0 == tgt -> no spin; hbuf memset fresh
  __syncthreads();

  for (int tl = 0; tl < TC_; ++tl) {
    const int par = tl & 1;

    // ---- MFMA phase: swizzled ds_read_b128 (conflict-free), B resident ----
    f32x4 e0 = {0.f, 0.f, 0.f, 0.f};
    f32x4 e1 = {0.f, 0.f, 0.f, 0.f};
    #pragma unroll
    for (int kk = 0; kk < 16; kk += 2) {
      const int c0 = kh * 64 + kk * 4 + (l >> 4);
      const int c1 = c0 + 4;
      const int sw0 = (l & 15) ^ ((2 * kk + (l >> 5)) & 7);
      const int sw1 = (l & 15) ^ ((2 * (kk + 1) + (l >> 5)) & 7);
      bf16x8 a0 = *(const bf16x8*)((const char*)Astg + ((size_t)(c0 * 16 + sw0) << 4));
      bf16x8 a1 = *(const bf16x8*)((const char*)Astg + ((size_t)(c1 * 16 + sw1) << 4));
      e0 = __builtin_amdgcn_mfma_f32_16x16x32_bf16(a0, bfr[kk],     e0, 0, 0, 0);
      e1 = __builtin_amdgcn_mfma_f32_16x16x32_bf16(a1, bfr[kk + 1], e1, 0, 0, 0);
    }
    f32x4 e = e0 + e1;
    #pragma unroll
    for (int r = 0; r < 4; ++r)
      part[kh][nt][((l >> 4) << 2) + r][l & 15] = e[r];
    __syncthreads();   // A: part visible; all Astg reads complete

    // ---- gate phase (waves 0..7) ----
    if (tid < 512) {
      const int sub = u >> 4, uc = u & 15;
      float gi = part[0][0 + sub][smg][uc] + part[1][0 + sub][smg][uc] + bf2f(x0);
      float gf = part[0][2 + sub][smg][uc] + part[1][2 + sub][smg][uc] + bf2f(x1);
      float gg = part[0][4 + sub][smg][uc] + part[1][4 + sub][smg][uc] + bf2f(x2);
      float go = part[0][6 + sub][smg][uc] + part[1][6 + sub][smg][uc] + bf2f(x3);
      cc = sigmoid_f(gf) * cc + sigmoid_f(gi) * tanh_f(gg);
      float hh = sigmoid_f(go) * tanh_f(cc);
      uint16_t hb = f2bf(hh);
      unsigned int o = (unsigned int)__shfl_xor((int)(unsigned int)hb, 1);
      if ((u & 1) == 0) {
        uint32_t pk = (uint32_t)hb | (o << 16);
        const int b = gs0 + smg;
        uint32_t* hp = hbuf + (size_t)(1 - par) * (B_ * H_ / 2)
                            + ((size_t)b * H_ + U0 + u) / 2;
        __hip_atomic_store(hp, pk, __ATOMIC_RELAXED, __HIP_MEMORY_SCOPE_SYSTEM);
        if (sall || (t0 + tl == T_ - 1)) {
          uint32_t* sq = (uint32_t*)seq + (((size_t)b * T_ + (t0 + tl)) * H_ + U0 + u) / 2;
          *sq = pk;
        }
      }
      if (tl + 1 < TC_) {   // xp prefetch after h-store issue
        const uint16_t* p = xp + ((size_t)(gs0 + smg) * TC_ + tl + 1) * G4_ + U0 + u;
        x0 = p[0]; x1 = p[1024]; x2 = p[2048]; x3 = p[3072];
      }
    }
    __syncthreads();   // B: drains vmcnt -> h stores MALL-visible
    if (tid == 0)
      __hip_atomic_store(gflag + s5, (unsigned)(tl + 1),
                         __ATOMIC_RELAXED, __HIP_MEMORY_SCOPE_SYSTEM);
    if (tl + 1 < TC_) {
      stage_fused(tl + 1);   // fused poll+load+swizzled LDS write
      __syncthreads();       // C: Astg ready for next MFMA
    }
  }
  if (tid < 512) cbuf[(size_t)(gs0 + smg) * H_ + U0 + u] = cc;
}

// ---------------- MLP head ----------------
__global__ __launch_bounds__(256) void k_mlp(
    const uint16_t* __restrict__ seq2,
    const float* __restrict__ w1, const float* __restrict__ b1,
    const float* __restrict__ w2, const float* __restrict__ b2,
    float* __restrict__ out)
{
  __shared__ float hv[H_];
  __shared__ float part[32][8];
  __shared__ float hid[32];
  const int b = blockIdx.x, tid = threadIdx.x;
  const uint16_t* hrow = seq2 + ((size_t)b * T_ + (T_ - 1)) * H_;
  for (int i = tid; i < H_; i += 256) hv[i] = bf2f(hrow[i]);
  __syncthreads();
  const int j = tid >> 3, p = tid & 7;
  float sum = 0.f;
  const float* wr = w1 + (size_t)j * H_ + p * 128;
  const float* hp = hv + p * 128;
  for (int k = 0; k < 128; ++k) sum += wr[k] * hp[k];
  part[j][p] = sum;
  __syncthreads();
  if (tid < 32) {
    float s2 = 0.f;
    #pragma unroll
    for (int pp = 0; pp < 8; ++pp) s2 += part[tid][pp];
    hid[tid] = fmaxf(s2 + b1[tid], 0.f);
  }
  __syncthreads();
  if (tid < 10) {
    float o = b2[tid];
    #pragma unroll
    for (int jj = 0; jj < 32; ++jj) o += hid[jj] * w2[tid * 32 + jj];
    out[b * 10 + tid] = o;
  }
}

// ---------------- launch ----------------
extern "C" void kernel_launch(void* const* d_in, const int* in_sizes, int n_in,
                              void* d_out, int out_size, void* d_ws, size_t ws_size,
                              hipStream_t stream)
{
  const float* x = (const float*)d_in[0];
  const float* w_ih[3] = {(const float*)d_in[1], (const float*)d_in[5], (const float*)d_in[9]};
  const float* w_hh[3] = {(const float*)d_in[2], (const float*)d_in[6], (const float*)d_in[10]};
  const float* b_ih[3] = {(const float*)d_in[3], (const float*)d_in[7], (const float*)d_in[11]};
  const float* b_hh[3] = {(const float*)d_in[4], (const float*)d_in[8], (const float*)d_in[12]};
  const float* w1 = (const float*)d_in[13];
  const float* b1 = (const float*)d_in[14];
  const float* w2 = (const float*)d_in[15];
  const float* b2 = (const float*)d_in[16];
  float* out = (float*)d_out;

  char* ws = (char*)d_ws;
  size_t off = 0;
  auto alloc = [&](size_t bytes) {
    char* p = ws + off;
    off += (bytes + 255) & ~(size_t)255;
    return p;
  };
  uint16_t* XBF  = (uint16_t*)alloc((size_t)B_ * T_ * IN_ * 2);
  uint16_t* WIH0 = (uint16_t*)alloc((size_t)G4_ * IN_ * 2);
  uint16_t* WIH1 = (uint16_t*)alloc((size_t)G4_ * H_ * 2);
  uint16_t* WIH2 = (uint16_t*)alloc((size_t)G4_ * H_ * 2);
  float*    BIAS = (float*)alloc((size_t)3 * G4_ * 4);
  uint16_t* WHHF = (uint16_t*)alloc((size_t)3 * G4_ * H_ * 2);
  uint16_t* XP   = (uint16_t*)alloc((size_t)B_ * TC_ * G4_ * 2);
  uint16_t* SEQ  = (uint16_t*)alloc((size_t)B_ * T_ * H_ * 2);
  uint32_t* HBUF = (uint32_t*)alloc((size_t)2 * B_ * H_ * 2);
  float*    CBUF = (float*)alloc((size_t)B_ * H_ * 4);
  unsigned int* FLG = (unsigned int*)alloc((size_t)3 * NCHUNK_ * 1024 * 4);

  hipMemsetAsync(FLG, 0, (size_t)3 * NCHUNK_ * 1024 * 4, stream);

  int n;
  n = B_ * T_ * IN_;
  k_f32_to_bf16<<<n / 4 / 256, 256, 0, stream>>>(x, XBF, n);
  // w_ih in MFMA-fragment order (conflict-free gemm B reads)
  k_wih_frag<<<(G4_ * IN_ / 8) / 256, 256, 0, stream>>>(w_ih[0], WIH0, IN_);
  k_wih_frag<<<(G4_ * H_ / 8) / 256, 256, 0, stream>>>(w_ih[1], WIH1, H_);
  k_wih_frag<<<(G4_ * H_ / 8) / 256, 256, 0, stream>>>(w_ih[2], WIH2, H_);
  for (int li = 0; li < 3; ++li)
    k_bias<<<16, 256, 0, stream>>>(b_ih[li], b_hh[li], BIAS + li * G4_);
  for (int li = 0; li < 3; ++li)
    k_whh_frag<<<2048, 256, 0, stream>>>(w_hh[li], WHHF + (size_t)li * G4_ * H_);

  const uint16_t* seq_in[3] = {XBF, SEQ, SEQ};
  const uint16_t* wih[3] = {WIH0, WIH1, WIH2};
  const int Ks[3] = {IN_, H_, H_};

  for (int li = 0; li < 3; ++li) {
    hipMemsetAsync(HBUF, 0, (size_t)2 * B_ * H_ * 2, stream);
    hipMemsetAsync(CBUF, 0, (size_t)B_ * H_ * 4, stream);
    const int sall = (li == 2) ? 0 : 1;
    for (int c = 0; c < NCHUNK_; ++c) {
      dim3 grid(64, 32);
      k_gemm_xp<<<grid, 256, 0, stream>>>(seq_in[li], wih[li], BIAS + li * G4_, XP,
                                          Ks[li], c * TC_);
      unsigned int* flg_lc = FLG + (size_t)(li * NCHUNK_ + c) * 1024;
      k_lstm<<<256, 1024, 0, stream>>>(WHHF + (size_t)li * G4_ * H_, XP, SEQ, HBUF,
                                       CBUF, flg_lc, c * TC_, sall);
    }
  }
  k_mlp<<<B_, 256, 0, stream>>>(SEQ, w1, b1, w2, b2, out);
}

// Round 19
// 3258.234 us; speedup vs baseline: 1.3168x; 1.0065x over previous
//
#include <hip/hip_runtime.h>
#include <hip/hip_bf16.h>
#include <stdint.h>

#define B_ 128
#define T_ 256
#define IN_ 512
#define H_ 1024
#define G4_ 4096
#define TC_ 64              // time chunk
#define NCHUNK_ (T_ / TC_)

typedef __bf16 bf16x8 __attribute__((ext_vector_type(8)));
typedef float f32x4 __attribute__((ext_vector_type(4)));
typedef uint32_t u32x4 __attribute__((ext_vector_type(4)));

#define AS1U(p) ((const __attribute__((address_space(1))) unsigned int*)(p))
#define AS3U(p) ((__attribute__((address_space(3))) unsigned int*)(p))

__device__ __forceinline__ uint16_t f2bf(float f) {
  union { float f; uint32_t u; } v; v.f = f;
  uint32_t r = (v.u + 0x7fffu + ((v.u >> 16) & 1u)) >> 16;
  return (uint16_t)r;
}
__device__ __forceinline__ float bf2f(uint16_t h) {
  union { uint32_t u; float f; } v; v.u = ((uint32_t)h) << 16;
  return v.f;
}
__device__ __forceinline__ float sigmoid_f(float x) {
  return 1.f / (1.f + __expf(-x));
}
__device__ __forceinline__ float tanh_f(float x) {
  x = fminf(15.f, fmaxf(-15.f, x));
  float e = __expf(2.f * x);
  return (e - 1.f) / (e + 1.f);
}

// ---------------- prep kernels ----------------
__global__ void k_f32_to_bf16(const float* __restrict__ src, uint16_t* __restrict__ dst, int n) {
  int i = (blockIdx.x * blockDim.x + threadIdx.x) * 4;
  if (i >= n) return;
  float4 v = *(const float4*)(src + i);
  ushort4 o;
  o.x = f2bf(v.x); o.y = f2bf(v.y); o.z = f2bf(v.z); o.w = f2bf(v.w);
  *(ushort4*)(dst + i) = o;
}

__global__ void k_bias(const float* __restrict__ a, const float* __restrict__ b, float* __restrict__ o) {
  int i = blockIdx.x * blockDim.x + threadIdx.x;
  if (i < G4_) o[i] = a[i] + b[i];
}

// Rearrange w_hh (fp32 [4096][1024]) into per-(slice,wave) MFMA B-fragments, bf16.
__global__ void k_whh_frag(const float* __restrict__ whh, uint16_t* __restrict__ dst) {
  int t = blockIdx.x * blockDim.x + threadIdx.x;   // 0..524287
  int lane = t & 63;
  int kk = (t >> 6) & 15;
  int w  = (t >> 10) & 15;
  int s5 = t >> 14;
  int nt = w & 7, kh = w >> 3;
  int row = (nt >> 1) * 1024 + s5 * 32 + (nt & 1) * 16 + (lane & 15);
  int col = kh * 512 + kk * 32 + ((lane >> 4) << 3);
  const float* sp = whh + (size_t)row * H_ + col;
  uint16_t o[8];
  #pragma unroll
  for (int j = 0; j < 8; ++j) o[j] = f2bf(sp[j]);
  uint4 pk;
  __builtin_memcpy(&pk, o, 16);
  *(uint4*)(dst + (size_t)t * 8) = pk;
}

// Rearrange w_ih (fp32 [4096][K]) into MFMA-fragment order for the gemm:
// dst[((nt*(K/32) + kc)*8 + j2)*512 + lane*8 + e] =
//   bf16(w_ih[nt*128 + j2*16 + (lane&15)][kc*32 + (lane>>4)*8 + e])
__global__ void k_wih_frag(const float* __restrict__ wih, uint16_t* __restrict__ dst, int K) {
  int t = blockIdx.x * blockDim.x + threadIdx.x;   // 4096*K/8 threads
  int lane = t & 63;
  int j2 = (t >> 6) & 7;
  int kcq = t >> 9;
  int nkc = K >> 5;
  int kc = kcq % nkc;
  int nt = kcq / nkc;
  int row = nt * 128 + j2 * 16 + (lane & 15);
  int col = kc * 32 + ((lane >> 4) << 3);
  const float* sp = wih + (size_t)row * K + col;
  uint16_t o[8];
  #pragma unroll
  for (int j = 0; j < 8; ++j) o[j] = f2bf(sp[j]);
  uint4 pk;
  __builtin_memcpy(&pk, o, 16);
  *(uint4*)(dst + (size_t)t * 8) = pk;
}

// ---------------- input-projection GEMM ----------------
// Cs aliases As/Bs (34.8KB LDS, 4 blocks/CU). B pre-arranged fragment-order
// (lane-linear reads). A tile XOR-swizzled via SOURCE permutation
// (global_load_lds dest is lane-linear, so permute which 16B each lane loads):
//   LDS slot16 (row, q) holds global (row, q ^ ((row>>1)&3))
// -> fragment read slot = (l>>4) ^ ((l>>1)&3): 8 bank-quads x 2 lanes = free.
__global__ __launch_bounds__(256, 1) void k_gemm_xp(
    const uint16_t* __restrict__ A, const uint16_t* __restrict__ WF,
    const float* __restrict__ bias, uint16_t* __restrict__ xp,
    int K, int t0)
{
  __shared__ __align__(16) char smem[128 * 136 * 2];   // 34816 B
  uint16_t* As = (uint16_t*)smem;                      // 8KB (K loop)
  uint16_t* Bs = (uint16_t*)(smem + 16384);            // 8KB fragment-order
  uint16_t* Cs = (uint16_t*)smem;                      // [128][136] epilogue
  const int tid = threadIdx.x;
  const int l = tid & 63;
  const int w = tid >> 6;
  const int mx = blockIdx.x;
  const int n0 = blockIdx.y * 128;
  const int wm = (w >> 1) * 64;
  const int wn = (w & 1) * 64;
  const int nkc = K >> 5;
  const int asl = (l >> 4) ^ ((l >> 1) & 3);   // un-swizzled A fragment slot

  f32x4 acc[4][4] = {};

  for (int k0 = 0; k0 < K; k0 += 32) {
    __syncthreads();
    // A tile: 8KB [128][32], stored source-swizzled
    #pragma unroll
    for (int it = 0; it < 2; ++it) {
      const int chunk = w * 2 + it;
      const int loff = chunk * 1024 + l * 16;  // byte offset in tile (dest)
      const int row = loff >> 6;               // 0..127
      const int slot = (loff >> 4) & 3;
      const int sslot = slot ^ ((row >> 1) & 3);
      const int gm = mx * 512 + t0 + ((row >> 6) << 8) + (row & 63);
      const uint16_t* ga = A + (size_t)gm * K + k0 + (sslot << 3);
      __builtin_amdgcn_global_load_lds(AS1U(ga), AS3U((char*)As + loff), 16, 0, 0);
    }
    // B tile: 8KB contiguous fragment-order chunk for (ntile=blockIdx.y, kc)
    {
      const uint16_t* gb = WF + (((size_t)blockIdx.y * nkc + (k0 >> 5)) << 12);
      #pragma unroll
      for (int rr = 0; rr < 2; ++rr) {
        const int boff = rr * 4096 + w * 1024 + l * 16;
        __builtin_amdgcn_global_load_lds(AS1U(gb + boff / 2),
                                         AS3U((char*)Bs + boff), 16, 0, 0);
      }
    }
    __syncthreads();
    bf16x8 af[4], bfr[4];
    #pragma unroll
    for (int i = 0; i < 4; ++i)
      af[i] = *(const bf16x8*)((const char*)As
                + (wm + i * 16 + (l & 15)) * 64 + asl * 16);
    #pragma unroll
    for (int j = 0; j < 4; ++j)
      bfr[j] = *(const bf16x8*)&Bs[((((w & 1) * 4 + j) * 64) + l) * 8];
    #pragma unroll
    for (int i = 0; i < 4; ++i) {
      #pragma unroll
      for (int j = 0; j < 4; ++j)
        acc[i][j] = __builtin_amdgcn_mfma_f32_16x16x32_bf16(af[i], bfr[j], acc[i][j], 0, 0, 0);
    }
  }
  __syncthreads();   // all fragment reads done -> safe to overwrite As/Bs as Cs

  // stage (acc + bias) -> bf16 into Cs (wave-exclusive subtile)
  #pragma unroll
  for (int i = 0; i < 4; ++i) {
    const int row = wm + i * 16 + ((l >> 4) << 2);
    #pragma unroll
    for (int j = 0; j < 4; ++j) {
      const int col = wn + j * 16 + (l & 15);
      const float bv = bias[n0 + col];
      #pragma unroll
      for (int r = 0; r < 4; ++r)
        Cs[(row + r) * 136 + col] = f2bf(acc[i][j][r] + bv);
    }
  }
  __syncthreads();
  // coalesced store: lane l -> row it*16 + w*4 + (l>>4), cols (l&15)*8..+7
  #pragma unroll
  for (int it = 0; it < 8; ++it) {
    const int row = it * 16 + w * 4 + (l >> 4);
    uint4 v = *(const uint4*)&Cs[row * 136 + (l & 15) * 8];
    *(uint4*)(xp + (size_t)(mx * 128 + row) * G4_ + n0 + (l & 15) * 8) = v;
  }
}

// ---------------- persistent LSTM recurrence ----------------
// Round-11 protocol verbatim (measured optimum: 203-207us, 3.2us/step).
__global__ __launch_bounds__(1024, 4) void k_lstm(
    const uint16_t* __restrict__ whhf, const uint16_t* __restrict__ xp,
    uint16_t* __restrict__ seq, uint32_t* __restrict__ hbuf,
    float* __restrict__ cbuf, unsigned int* __restrict__ flags, int t0, int sall)
{
  __shared__ __align__(16) uint16_t Astg[2048 * 8];     // 32 KiB swizzled slots
  __shared__ float part[2][8][16][17];                  // 17.4 KiB
  const int tid = threadIdx.x;
  const int l = tid & 63;
  const int w = tid >> 6;           // 0..15: stage row; mfma: nt=w&7, kh=w>>3
  const int nt = w & 7;
  const int kh = w >> 3;
  const int bid = blockIdx.x;
  const int g = bid & 7;
  const int s5 = bid >> 3;          // 0..31
  const int U0 = s5 * 32;
  const int gs0 = g * 16;

  unsigned int* gflag = flags + g * 32;

  // resident weight fragments (64 VGPR/lane)
  bf16x8 bfr[16];
  {
    const uint16_t* wp = whhf + (size_t)(s5 * 16 + w) * 8192 + l * 8;
    #pragma unroll
    for (int kk = 0; kk < 16; ++kk)
      bfr[kk] = *(const bf16x8*)(wp + kk * 512);
  }

  const int u = tid & 31;
  const int smg = (tid >> 5) & 15;
  float cc = 0.f;
  if (tid < 512) cc = cbuf[(size_t)(gs0 + smg) * H_ + U0 + u];

  uint16_t x0 = 0, x1 = 0, x2 = 0, x3 = 0;
  if (tid < 512) {
    const uint16_t* p = xp + ((size_t)(gs0 + smg) * TC_ + 0) * G4_ + U0 + u;
    x0 = p[0]; x1 = p[1024]; x2 = p[2048]; x3 = p[3072];
  }

  // fused poll+stage of state tl: wave w = sample row gs0+w, lane l = 32B at
  // col l*32 (units 16l..16l+15, produced by slice l>>1). Per-lane validated
  // retry; first try succeeds in steady state -> stage costs ~1 MALL RTT.
  auto stage_fused = [&](int tl) {
    const int par = tl & 1;
    const unsigned tgt = (unsigned)tl;   // chunk-local state index
    const char* src = (const char*)hbuf + (size_t)par * (B_ * H_ * 2)
                      + (size_t)(gs0 + w) * 2048 + (size_t)l * 32;
    const unsigned int* fp = gflag + (l >> 1);
    u32x4 q0, q1;
    unsigned fv;
    do {
      asm volatile(
        "global_load_dword %0, %3, off sc0 sc1\n\t"
        "global_load_dwordx4 %1, %4, off sc0 sc1\n\t"
        "global_load_dwordx4 %2, %4, off offset:16 sc0 sc1\n\t"
        "s_waitcnt vmcnt(0)"
        : "=&v"(fv), "=&v"(q0), "=&v"(q1)
        : "v"(fp), "v"(src)
        : "memory");
      if (fv >= tgt) break;
      __builtin_amdgcn_s_sleep(1);
    } while (true);
    const int base = 512 * l + ((w ^ (l & 7)) << 4);
    *(u32x4*)((char*)Astg + base) = q0;
    *(u32x4*)((char*)Astg + base + 256) = q1;
  };

  stage_fused(0);    // flags start at 0 == tgt -> no spin; hbuf memset fresh
  __syncthreads();

  for (int tl = 0; tl < TC_; ++tl) {
    const int par = tl & 1;

    // ---- MFMA phase: swizzled ds_read_b128 (conflict-free), B resident ----
    f32x4 e0 = {0.f, 0.f, 0.f, 0.f};
    f32x4 e1 = {0.f, 0.f, 0.f, 0.f};
    #pragma unroll
    for (int kk = 0; kk < 16; kk += 2) {
      const int c0 = kh * 64 + kk * 4 + (l >> 4);
      const int c1 = c0 + 4;
      const int sw0 = (l & 15) ^ ((2 * kk + (l >> 5)) & 7);
      const int sw1 = (l & 15) ^ ((2 * (kk + 1) + (l >> 5)) & 7);
      bf16x8 a0 = *(const bf16x8*)((const char*)Astg + ((size_t)(c0 * 16 + sw0) << 4));
      bf16x8 a1 = *(const bf16x8*)((const char*)Astg + ((size_t)(c1 * 16 + sw1) << 4));
      e0 = __builtin_amdgcn_mfma_f32_16x16x32_bf16(a0, bfr[kk],     e0, 0, 0, 0);
      e1 = __builtin_amdgcn_mfma_f32_16x16x32_bf16(a1, bfr[kk + 1], e1, 0, 0, 0);
    }
    f32x4 e = e0 + e1;
    #pragma unroll
    for (int r = 0; r < 4; ++r)
      part[kh][nt][((l >> 4) << 2) + r][l & 15] = e[r];
    __syncthreads();   // A: part visible; all Astg reads complete

    // ---- gate phase (waves 0..7) ----
    if (tid < 512) {
      const int sub = u >> 4, uc = u & 15;
      float gi = part[0][0 + sub][smg][uc] + part[1][0 + sub][smg][uc] + bf2f(x0);
      float gf = part[0][2 + sub][smg][uc] + part[1][2 + sub][smg][uc] + bf2f(x1);
      float gg = part[0][4 + sub][smg][uc] + part[1][4 + sub][smg][uc] + bf2f(x2);
      float go = part[0][6 + sub][smg][uc] + part[1][6 + sub][smg][uc] + bf2f(x3);
      cc = sigmoid_f(gf) * cc + sigmoid_f(gi) * tanh_f(gg);
      float hh = sigmoid_f(go) * tanh_f(cc);
      uint16_t hb = f2bf(hh);
      unsigned int o = (unsigned int)__shfl_xor((int)(unsigned int)hb, 1);
      if ((u & 1) == 0) {
        uint32_t pk = (uint32_t)hb | (o << 16);
        const int b = gs0 + smg;
        uint32_t* hp = hbuf + (size_t)(1 - par) * (B_ * H_ / 2)
                            + ((size_t)b * H_ + U0 + u) / 2;
        __hip_atomic_store(hp, pk, __ATOMIC_RELAXED, __HIP_MEMORY_SCOPE_SYSTEM);
        if (sall || (t0 + tl == T_ - 1)) {
          uint32_t* sq = (uint32_t*)seq + (((size_t)b * T_ + (t0 + tl)) * H_ + U0 + u) / 2;
          *sq = pk;
        }
      }
      if (tl + 1 < TC_) {   // xp prefetch after h-store issue
        const uint16_t* p = xp + ((size_t)(gs0 + smg) * TC_ + tl + 1) * G4_ + U0 + u;
        x0 = p[0]; x1 = p[1024]; x2 = p[2048]; x3 = p[3072];
      }
    }
    __syncthreads();   // B: drains vmcnt -> h stores MALL-visible
    if (tid == 0)
      __hip_atomic_store(gflag + s5, (unsigned)(tl + 1),
                         __ATOMIC_RELAXED, __HIP_MEMORY_SCOPE_SYSTEM);
    if (tl + 1 < TC_) {
      stage_fused(tl + 1);   // fused poll+load+swizzled LDS write
      __syncthreads();       // C: Astg ready for next MFMA
    }
  }
  if (tid < 512) cbuf[(size_t)(gs0 + smg) * H_ + U0 + u] = cc;
}

// ---------------- MLP head ----------------
__global__ __launch_bounds__(256) void k_mlp(
    const uint16_t* __restrict__ seq2,
    const float* __restrict__ w1, const float* __restrict__ b1,
    const float* __restrict__ w2, const float* __restrict__ b2,
    float* __restrict__ out)
{
  __shared__ float hv[H_];
  __shared__ float part[32][8];
  __shared__ float hid[32];
  const int b = blockIdx.x, tid = threadIdx.x;
  const uint16_t* hrow = seq2 + ((size_t)b * T_ + (T_ - 1)) * H_;
  for (int i = tid; i < H_; i += 256) hv[i] = bf2f(hrow[i]);
  __syncthreads();
  const int j = tid >> 3, p = tid & 7;
  float sum = 0.f;
  const float* wr = w1 + (size_t)j * H_ + p * 128;
  const float* hp = hv + p * 128;
  for (int k = 0; k < 128; ++k) sum += wr[k] * hp[k];
  part[j][p] = sum;
  __syncthreads();
  if (tid < 32) {
    float s2 = 0.f;
    #pragma unroll
    for (int pp = 0; pp < 8; ++pp) s2 += part[tid][pp];
    hid[tid] = fmaxf(s2 + b1[tid], 0.f);
  }
  __syncthreads();
  if (tid < 10) {
    float o = b2[tid];
    #pragma unroll
    for (int jj = 0; jj < 32; ++jj) o += hid[jj] * w2[tid * 32 + jj];
    out[b * 10 + tid] = o;
  }
}

// ---------------- launch ----------------
extern "C" void kernel_launch(void* const* d_in, const int* in_sizes, int n_in,
                              void* d_out, int out_size, void* d_ws, size_t ws_size,
                              hipStream_t stream)
{
  const float* x = (const float*)d_in[0];
  const float* w_ih[3] = {(const float*)d_in[1], (const float*)d_in[5], (const float*)d_in[9]};
  const float* w_hh[3] = {(const float*)d_in[2], (const float*)d_in[6], (const float*)d_in[10]};
  const float* b_ih[3] = {(const float*)d_in[3], (const float*)d_in[7], (const float*)d_in[11]};
  const float* b_hh[3] = {(const float*)d_in[4], (const float*)d_in[8], (const float*)d_in[12]};
  const float* w1 = (const float*)d_in[13];
  const float* b1 = (const float*)d_in[14];
  const float* w2 = (const float*)d_in[15];
  const float* b2 = (const float*)d_in[16];
  float* out = (float*)d_out;

  char* ws = (char*)d_ws;
  size_t off = 0;
  auto alloc = [&](size_t bytes) {
    char* p = ws + off;
    off += (bytes + 255) & ~(size_t)255;
    return p;
  };
  uint16_t* XBF  = (uint16_t*)alloc((size_t)B_ * T_ * IN_ * 2);
  uint16_t* WIH0 = (uint16_t*)alloc((size_t)G4_ * IN_ * 2);
  uint16_t* WIH1 = (uint16_t*)alloc((size_t)G4_ * H_ * 2);
  uint16_t* WIH2 = (uint16_t*)alloc((size_t)G4_ * H_ * 2);
  float*    BIAS = (float*)alloc((size_t)3 * G4_ * 4);
  uint16_t* WHHF = (uint16_t*)alloc((size_t)3 * G4_ * H_ * 2);
  uint16_t* XP   = (uint16_t*)alloc((size_t)B_ * TC_ * G4_ * 2);
  uint16_t* SEQ  = (uint16_t*)alloc((size_t)B_ * T_ * H_ * 2);
  uint32_t* HBUF = (uint32_t*)alloc((size_t)2 * B_ * H_ * 2);
  float*    CBUF = (float*)alloc((size_t)B_ * H_ * 4);
  unsigned int* FLG = (unsigned int*)alloc((size_t)3 * NCHUNK_ * 1024 * 4);

  hipMemsetAsync(FLG, 0, (size_t)3 * NCHUNK_ * 1024 * 4, stream);

  int n;
  n = B_ * T_ * IN_;
  k_f32_to_bf16<<<n / 4 / 256, 256, 0, stream>>>(x, XBF, n);
  // w_ih in MFMA-fragment order (conflict-free gemm B reads)
  k_wih_frag<<<(G4_ * IN_ / 8) / 256, 256, 0, stream>>>(w_ih[0], WIH0, IN_);
  k_wih_frag<<<(G4_ * H_ / 8) / 256, 256, 0, stream>>>(w_ih[1], WIH1, H_);
  k_wih_frag<<<(G4_ * H_ / 8) / 256, 256, 0, stream>>>(w_ih[2], WIH2, H_);
  for (int li = 0; li < 3; ++li)
    k_bias<<<16, 256, 0, stream>>>(b_ih[li], b_hh[li], BIAS + li * G4_);
  for (int li = 0; li < 3; ++li)
    k_whh_frag<<<2048, 256, 0, stream>>>(w_hh[li], WHHF + (size_t)li * G4_ * H_);

  const uint16_t* seq_in[3] = {XBF, SEQ, SEQ};
  const uint16_t* wih[3] = {WIH0, WIH1, WIH2};
  const int Ks[3] = {IN_, H_, H_};

  for (int li = 0; li < 3; ++li) {
    hipMemsetAsync(HBUF, 0, (size_t)2 * B_ * H_ * 2, stream);
    hipMemsetAsync(CBUF, 0, (size_t)B_ * H_ * 4, stream);
    const int sall = (li == 2) ? 0 : 1;
    for (int c = 0; c < NCHUNK_; ++c) {
      dim3 grid(64, 32);
      k_gemm_xp<<<grid, 256, 0, stream>>>(seq_in[li], wih[li], BIAS + li * G4_, XP,
                                          Ks[li], c * TC_);
      unsigned int* flg_lc = FLG + (size_t)(li * NCHUNK_ + c) * 1024;
      k_lstm<<<256, 1024, 0, stream>>>(WHHF + (size_t)li * G4_ * H_, XP, SEQ, HBUF,
                                       CBUF, flg_lc, c * TC_, sall);
    }
  }
  k_mlp<<<B_, 256, 0, stream>>>(SEQ, w1, b1, w2, b2, out);
}